// Round 1
// baseline (7993.961 us; speedup 1.0000x reference)
//
#include <hip/hip_runtime.h>
#include <stdint.h>

#define B_ 64
#define T_ 2048
#define F_ 128
#define H_ 256
#define TC_ 1022

typedef __bf16 bf16x8 __attribute__((ext_vector_type(8)));
typedef float f32x4 __attribute__((ext_vector_type(4)));

__device__ __forceinline__ ushort f2bf(float f) {
    uint32_t u = __builtin_bit_cast(uint32_t, f);
    u += 0x7FFFu + ((u >> 16) & 1u);
    return (ushort)(u >> 16);
}
__device__ __forceinline__ float sigmoidf_(float x) { return 1.f / (1.f + __expf(-x)); }
__device__ __forceinline__ float tanhf_(float x) {
    x = fminf(15.f, fmaxf(-15.f, x));
    float e = __expf(2.f * x);
    return (e - 1.f) / (e + 1.f);
}

// ---- Kernel 1: sum of squares over T for F.normalize(dim=1) ----
// grid 1024 = 64 b * 16 t-quarters, 128 threads (thread = f)
__global__ __launch_bounds__(128) void k_sqsum(const float* __restrict__ in,
                                               float* __restrict__ sq) {
    int b = blockIdx.x >> 4, tq = blockIdx.x & 15, f = threadIdx.x;
    const float* p = in + ((size_t)b * T_ + (size_t)tq * 128) * F_ + f;
    float acc = 0.f;
#pragma unroll 8
    for (int t = 0; t < 128; ++t) { float v = p[(size_t)t * F_]; acc += v * v; }
    atomicAdd(&sq[b * F_ + f], acc);
}

// ---- Kernel 2: weight repack to bf16, block-row order; bias combine ----
// W_bf[g][m][k], g=block(4 units), m = uu*4+gate (so MFMA acc reg = gate), k: [0,64)=w_ih, [64,320)=w_hh
__global__ __launch_bounds__(256) void k_prep(const float* __restrict__ wih, const float* __restrict__ whh,
                                              const float* __restrict__ bih, const float* __restrict__ bhh,
                                              ushort* __restrict__ wbf, float* __restrict__ bias) {
    int e = blockIdx.x * 256 + threadIdx.x;
    if (e < 64 * 16 * 320) {
        int g = e / 5120, m = (e / 320) & 15, k = e % 320;
        int j = (m & 3) * 256 + g * 4 + (m >> 2);  // gate*256 + unit
        float v = (k < 64) ? wih[j * 64 + k] : whh[j * 256 + (k - 64)];
        wbf[e] = f2bf(v);
    }
    if (e < 1024) bias[e] = bih[e] + bhh[e];
}

// ---- Kernel 3: fused normalize + conv1d(K=5,S=2) + bias + relu -> lstm_in bf16 [tc][b][72pad] ----
// grid 2048 = 64 b * 32 tc-tiles(32), 256 threads = 16 c-groups(4c) x 16 tc-groups(2tc)
__global__ __launch_bounds__(256) void k_conv(const float* __restrict__ in, const float* __restrict__ cw,
                                              const float* __restrict__ cb, const float* __restrict__ sq,
                                              ushort* __restrict__ li) {
    __shared__ float rn[128];
    __shared__ __align__(16) float xs[67 * 129];   // padded rows: bank-spread
    __shared__ __align__(16) float wl[80 * 68];    // [j=frel*5+k][c], pad 68 for b128-friendly banks
    int b = blockIdx.x >> 5, tile = blockIdx.x & 31;
    int tc0 = tile * 32;
    int tid = threadIdx.x;
    if (tid < 128) { float ss = sq[b * 128 + tid]; rn[tid] = 1.f / fmaxf(sqrtf(ss), 1e-12f); }
    __syncthreads();
    const float* ip = in + ((size_t)b * T_ + (size_t)(2 * tc0)) * F_;
    for (int i = tid; i < 67 * 128; i += 256) {
        int r = i >> 7, f = i & 127;
        int t = 2 * tc0 + r;
        xs[r * 129 + f] = (t < T_) ? ip[(size_t)r * F_ + f] * rn[f] : 0.f;
    }
    int cg = tid & 15, tcg = tid >> 4;
    float a00 = 0, a01 = 0, a10 = 0, a11 = 0, a20 = 0, a21 = 0, a30 = 0, a31 = 0;
    for (int fc = 0; fc < 8; ++fc) {
        __syncthreads();
        for (int i = tid; i < 64 * 80; i += 256) {
            int c = i / 80, j = i - c * 80;
            wl[j * 68 + c] = cw[c * 640 + fc * 80 + j];
        }
        __syncthreads();
#pragma unroll
        for (int fi = 0; fi < 16; ++fi) {
#pragma unroll
            for (int k = 0; k < 5; ++k) {
                const float4 w4 = *(const float4*)&wl[(fi * 5 + k) * 68 + cg * 4];
                float x0 = xs[(4 * tcg + k) * 129 + fc * 16 + fi];
                float x1 = xs[(4 * tcg + 2 + k) * 129 + fc * 16 + fi];
                a00 += w4.x * x0; a01 += w4.x * x1;
                a10 += w4.y * x0; a11 += w4.y * x1;
                a20 += w4.z * x0; a21 += w4.z * x1;
                a30 += w4.w * x0; a31 += w4.w * x1;
            }
        }
    }
    float bc0 = cb[cg * 4 + 0], bc1 = cb[cg * 4 + 1], bc2 = cb[cg * 4 + 2], bc3 = cb[cg * 4 + 3];
#pragma unroll
    for (int tt = 0; tt < 2; ++tt) {
        int tc = tc0 + tcg * 2 + tt;
        if (tc < TC_) {
            float v0 = fmaxf((tt ? a01 : a00) + bc0, 0.f);
            float v1 = fmaxf((tt ? a11 : a10) + bc1, 0.f);
            float v2 = fmaxf((tt ? a21 : a20) + bc2, 0.f);
            float v3 = fmaxf((tt ? a31 : a30) + bc3, 0.f);
            uint2 pk;
            pk.x = (uint32_t)f2bf(v0) | ((uint32_t)f2bf(v1) << 16);
            pk.y = (uint32_t)f2bf(v2) | ((uint32_t)f2bf(v3) << 16);
            *reinterpret_cast<uint2*>(&li[((size_t)tc * 64 + b) * 72 + cg * 4]) = pk;
        }
    }
}

// ---- Kernel 4: persistent LSTM scan. 64 blocks x 256 threads. Block g owns units [4g,4g+4).
// Wave w handles batches [16w,16w+16) (MFMA N-tile); M=16 gate-rows; K=320. Lane (quad,l16):
// acc regs 0..3 = gates i,f,g,o for (batch=16w+l16, unit=4g+quad); c-state in 1 VGPR.
__global__ __launch_bounds__(256) void k_scan(const ushort* __restrict__ li, const ushort* __restrict__ wbf,
                                              const float* __restrict__ bias, ushort* hb0, ushort* hb1,
                                              float* __restrict__ hfin, int* __restrict__ cnt) {
    __shared__ __align__(16) ushort Blx[64 * 72];    // xt [b][72pad]
    __shared__ __align__(16) ushort Blh[64 * 288];   // h  [b][288pad]  (576B rows -> 2-way banks, free)
    int g = blockIdx.x;
    int tid = threadIdx.x;
    int wave = tid >> 6, lane = tid & 63, l16 = lane & 15, quad = lane >> 4;
    int bb = wave * 16 + l16;
    int u = g * 4 + quad;
    // A-fragments (weights) are loop-invariant: keep in registers for the whole scan.
    bf16x8 af[10];
    const ushort* wp = wbf + ((size_t)g * 16 + l16) * 320 + quad * 8;
#pragma unroll
    for (int s = 0; s < 10; ++s) af[s] = *(const bf16x8*)(wp + s * 32);
    float bi = bias[u], bf = bias[256 + u], bg = bias[512 + u], bo = bias[768 + u];
    float cs = 0.f;
    for (int t = 0; t < TC_; ++t) {
        __syncthreads();
        // stage xt + h into LDS: both straight linear uint4 copies
        const uint4* xsrc = (const uint4*)(li + (size_t)t * 4608);
        uint4* xdst = (uint4*)Blx;
        for (int idx = tid; idx < 576; idx += 256) xdst[idx] = xsrc[idx];
        const uint4* hsrc = (const uint4*)((t & 1) ? hb1 : hb0);
        uint4* hdst = (uint4*)Blh;
        for (int idx = tid; idx < 2304; idx += 256) hdst[idx] = hsrc[idx];
        __syncthreads();
        f32x4 acc = {0.f, 0.f, 0.f, 0.f};
        const ushort* bx = &Blx[bb * 72 + quad * 8];
        const ushort* bh = &Blh[bb * 288 + quad * 8];
        acc = __builtin_amdgcn_mfma_f32_16x16x32_bf16(af[0], *(const bf16x8*)(bx), acc, 0, 0, 0);
        acc = __builtin_amdgcn_mfma_f32_16x16x32_bf16(af[1], *(const bf16x8*)(bx + 32), acc, 0, 0, 0);
#pragma unroll
        for (int s = 0; s < 8; ++s)
            acc = __builtin_amdgcn_mfma_f32_16x16x32_bf16(af[2 + s], *(const bf16x8*)(bh + s * 32), acc, 0, 0, 0);
        float gi = acc[0] + bi, gf = acc[1] + bf, gg = acc[2] + bg, go = acc[3] + bo;
        float ii = sigmoidf_(gi), ff = sigmoidf_(gf), g2 = tanhf_(gg), oo = sigmoidf_(go);
        cs = ff * cs + ii * g2;
        float hv = oo * tanhf_(cs);
        ushort* hwr = (t & 1) ? hb0 : hb1;  // h_buf[(t+1)&1]
        hwr[bb * 288 + u] = f2bf(hv);
        if (t == TC_ - 1) {
            hfin[u * 64 + bb] = hv;  // fp32 final h, [u][b] for coalesced consumer
        } else {
            __syncthreads();  // all stores of this block issued
            if (tid == 0) {
                __hip_atomic_fetch_add(&cnt[t], 1, __ATOMIC_RELEASE, __HIP_MEMORY_SCOPE_AGENT);
                while (__hip_atomic_load(&cnt[t], __ATOMIC_ACQUIRE, __HIP_MEMORY_SCOPE_AGENT) < 64) {}
            }
            __syncthreads();
        }
    }
}

// ---- Kernel 5: out[b][o] = h_final[:,b] . lin_w[o,:] + lin_b[o] ----
__global__ __launch_bounds__(64) void k_fin(const float* __restrict__ hfin, const float* __restrict__ lw,
                                            const float* __restrict__ lb, float* __restrict__ out) {
    int o = blockIdx.x, b = threadIdx.x;
    float acc = lb[o];
    const float* wp = lw + o * 256;
#pragma unroll 4
    for (int u2 = 0; u2 < 256; ++u2) acc += hfin[u2 * 64 + b] * wp[u2];
    out[b * 10 + o] = acc;
}

extern "C" void kernel_launch(void* const* d_in, const int* in_sizes, int n_in,
                              void* d_out, int out_size, void* d_ws, size_t ws_size,
                              hipStream_t stream) {
    const float* in  = (const float*)d_in[0];
    // d_in[1] ("r") unused
    const float* cw  = (const float*)d_in[2];
    const float* cb  = (const float*)d_in[3];
    const float* wih = (const float*)d_in[4];
    const float* whh = (const float*)d_in[5];
    const float* bih = (const float*)d_in[6];
    const float* bhh = (const float*)d_in[7];
    const float* lw  = (const float*)d_in[8];
    const float* lb  = (const float*)d_in[9];
    float* out = (float*)d_out;

    char* ws = (char*)d_ws;
    int*    cnt  = (int*)(ws + 0);            // 4096 B (1022 counters)
    float*  sq   = (float*)(ws + 4096);       // 32768 B
    ushort* hb0  = (ushort*)(ws + 36864);     // 36864 B  [b][288] bf16
    ushort* hb1  = (ushort*)(ws + 73728);     // 36864 B
    float*  bias = (float*)(ws + 110592);     // 4096 B
    float*  hfin = (float*)(ws + 114688);     // 65536 B  [u][b] fp32
    ushort* wbf  = (ushort*)(ws + 180224);    // 655360 B [g][16][320] bf16
    ushort* li   = (ushort*)(ws + 835584);    // 9418752 B [tc][b][72] bf16
    // total ws use ~10.3 MB

    hipMemsetAsync(d_ws, 0, 73728, stream);   // counters + sq + h_buf0(=h at t=0)

    k_sqsum<<<1024, 128, 0, stream>>>(in, sq);
    k_prep<<<1280, 256, 0, stream>>>(wih, whh, bih, bhh, wbf, bias);
    k_conv<<<2048, 256, 0, stream>>>(in, cw, cb, sq, li);
    k_scan<<<64, 256, 0, stream>>>(li, wbf, bias, hb0, hb1, hfin, cnt);
    k_fin<<<10, 64, 0, stream>>>(hfin, lw, lb, out);
}

// Round 2
// 7447.207 us; speedup vs baseline: 1.0734x; 1.0734x over previous
//
#include <hip/hip_runtime.h>
#include <stdint.h>

#define B_ 64
#define T_ 2048
#define F_ 128
#define H_ 256
#define TC_ 1022

typedef __bf16 bf16x8 __attribute__((ext_vector_type(8)));
typedef float f32x4 __attribute__((ext_vector_type(4)));
typedef unsigned long long u64;

__device__ __forceinline__ ushort f2bf(float f) {
    uint32_t u = __builtin_bit_cast(uint32_t, f);
    u += 0x7FFFu + ((u >> 16) & 1u);
    return (ushort)(u >> 16);
}
__device__ __forceinline__ float sigmoidf_(float x) { return 1.f / (1.f + __expf(-x)); }
__device__ __forceinline__ float tanhf_(float x) {
    x = fminf(15.f, fmaxf(-15.f, x));
    float e = __expf(2.f * x);
    return (e - 1.f) / (e + 1.f);
}

// ---- Kernel 1: sum of squares over T for F.normalize(dim=1) ----
__global__ __launch_bounds__(128) void k_sqsum(const float* __restrict__ in,
                                               float* __restrict__ sq) {
    int b = blockIdx.x >> 4, tq = blockIdx.x & 15, f = threadIdx.x;
    const float* p = in + ((size_t)b * T_ + (size_t)tq * 128) * F_ + f;
    float acc = 0.f;
#pragma unroll 8
    for (int t = 0; t < 128; ++t) { float v = p[(size_t)t * F_]; acc += v * v; }
    atomicAdd(&sq[b * F_ + f], acc);
}

// ---- Kernel 2: weight repack to bf16 block-row order; bias combine ----
__global__ __launch_bounds__(256) void k_prep(const float* __restrict__ wih, const float* __restrict__ whh,
                                              const float* __restrict__ bih, const float* __restrict__ bhh,
                                              ushort* __restrict__ wbf, float* __restrict__ bias) {
    int e = blockIdx.x * 256 + threadIdx.x;
    if (e < 64 * 16 * 320) {
        int g = e / 5120, m = (e / 320) & 15, k = e % 320;
        int j = (m & 3) * 256 + g * 4 + (m >> 2);  // gate*256 + unit
        float v = (k < 64) ? wih[j * 64 + k] : whh[j * 256 + (k - 64)];
        wbf[e] = f2bf(v);
    }
    if (e < 1024) bias[e] = bih[e] + bhh[e];
}

// ---- Kernel 3: fused normalize + conv1d(K=5,S=2) + bias + relu -> li bf16 [tc][b][72pad] ----
__global__ __launch_bounds__(256) void k_conv(const float* __restrict__ in, const float* __restrict__ cw,
                                              const float* __restrict__ cb, const float* __restrict__ sq,
                                              ushort* __restrict__ li) {
    __shared__ float rn[128];
    __shared__ __align__(16) float xs[67 * 129];
    __shared__ __align__(16) float wl[80 * 68];
    int b = blockIdx.x >> 5, tile = blockIdx.x & 31;
    int tc0 = tile * 32;
    int tid = threadIdx.x;
    if (tid < 128) { float ss = sq[b * 128 + tid]; rn[tid] = 1.f / fmaxf(sqrtf(ss), 1e-12f); }
    __syncthreads();
    const float* ip = in + ((size_t)b * T_ + (size_t)(2 * tc0)) * F_;
    for (int i = tid; i < 67 * 128; i += 256) {
        int r = i >> 7, f = i & 127;
        int t = 2 * tc0 + r;
        xs[r * 129 + f] = (t < T_) ? ip[(size_t)r * F_ + f] * rn[f] : 0.f;
    }
    int cg = tid & 15, tcg = tid >> 4;
    float a00 = 0, a01 = 0, a10 = 0, a11 = 0, a20 = 0, a21 = 0, a30 = 0, a31 = 0;
    for (int fc = 0; fc < 8; ++fc) {
        __syncthreads();
        for (int i = tid; i < 64 * 80; i += 256) {
            int c = i / 80, j = i - c * 80;
            wl[j * 68 + c] = cw[c * 640 + fc * 80 + j];
        }
        __syncthreads();
#pragma unroll
        for (int fi = 0; fi < 16; ++fi) {
#pragma unroll
            for (int k = 0; k < 5; ++k) {
                const float4 w4 = *(const float4*)&wl[(fi * 5 + k) * 68 + cg * 4];
                float x0 = xs[(4 * tcg + k) * 129 + fc * 16 + fi];
                float x1 = xs[(4 * tcg + 2 + k) * 129 + fc * 16 + fi];
                a00 += w4.x * x0; a01 += w4.x * x1;
                a10 += w4.y * x0; a11 += w4.y * x1;
                a20 += w4.z * x0; a21 += w4.z * x1;
                a30 += w4.w * x0; a31 += w4.w * x1;
            }
        }
    }
    float bc0 = cb[cg * 4 + 0], bc1 = cb[cg * 4 + 1], bc2 = cb[cg * 4 + 2], bc3 = cb[cg * 4 + 3];
#pragma unroll
    for (int tt = 0; tt < 2; ++tt) {
        int tc = tc0 + tcg * 2 + tt;
        if (tc < TC_) {
            float v0 = fmaxf((tt ? a01 : a00) + bc0, 0.f);
            float v1 = fmaxf((tt ? a11 : a10) + bc1, 0.f);
            float v2 = fmaxf((tt ? a21 : a20) + bc2, 0.f);
            float v3 = fmaxf((tt ? a31 : a30) + bc3, 0.f);
            uint2 pk;
            pk.x = (uint32_t)f2bf(v0) | ((uint32_t)f2bf(v1) << 16);
            pk.y = (uint32_t)f2bf(v2) | ((uint32_t)f2bf(v3) << 16);
            *reinterpret_cast<uint2*>(&li[((size_t)tc * 64 + b) * 72 + cg * 4]) = pk;
        }
    }
}

// ---- Kernel 4: wave-autonomous LSTM scan. 64 blocks x 256 thr. Block g owns units [4g,4g+4);
// wave w owns batches [16w,16w+16). No LDS, no syncthreads, no fences. h exchanged through
// LLC via relaxed agent atomics; each dword = bf16 h | (step_tag<<16), 8B stores single-copy
// atomic -> one tag check per ulong. Double-buffered by step parity; dataflow enforces WAR.
__global__ __launch_bounds__(256) void k_scan(const ushort* __restrict__ li,
                                              const ushort* __restrict__ wbf,
                                              const float* __restrict__ bias,
                                              u64* __restrict__ hbuf,
                                              float* __restrict__ hfin) {
    int g = blockIdx.x;
    int tid = threadIdx.x;
    int lane = tid & 63, wave = tid >> 6, l16 = lane & 15, quad = lane >> 4;
    int bb = wave * 16 + l16;
    int u = g * 4 + quad;
    // Stationary A-fragments (weights) for the whole scan.
    bf16x8 af[10];
    const ushort* wp = wbf + ((size_t)g * 16 + l16) * 320 + quad * 8;
#pragma unroll
    for (int s = 0; s < 10; ++s) af[s] = *(const bf16x8*)(wp + s * 32);
    float bi = bias[u], bf2 = bias[256 + u], bg = bias[512 + u], bo = bias[768 + u];
    float cs = 0.f;
#pragma unroll 1
    for (int t = 0; t < TC_; ++t) {
        // xt fragments: plain cached loads, independent of the h exchange -> issue first.
        const ushort* xp = li + ((size_t)t * 64 + bb) * 72 + quad * 8;
        bf16x8 bx0 = *(const bf16x8*)xp;
        bf16x8 bx1 = *(const bf16x8*)(xp + 32);
        f32x4 acc = {0.f, 0.f, 0.f, 0.f};
        f32x4 acc2 = {0.f, 0.f, 0.f, 0.f};
        acc = __builtin_amdgcn_mfma_f32_16x16x32_bf16(af[0], bx0, acc, 0, 0, 0);
        acc2 = __builtin_amdgcn_mfma_f32_16x16x32_bf16(af[1], bx1, acc2, 0, 0, 0);
        if (t > 0) {
            uint tg = (uint)(t - 1);
            const u64* base = hbuf + ((size_t)((t - 1) & 1) * 8192) + bb * 128 + quad * 4;
            u64 vv[32];
            bool ok;
            do {
#pragma unroll
                for (int s = 0; s < 8; ++s)
#pragma unroll
                    for (int j = 0; j < 4; ++j)
                        vv[s * 4 + j] = __hip_atomic_load(base + 16 * s + j,
                                                          __ATOMIC_RELAXED, __HIP_MEMORY_SCOPE_AGENT);
                uint m = 0;
#pragma unroll
                for (int i = 0; i < 32; ++i) m |= ((uint)(vv[i] >> 48)) ^ tg;
                ok = (m == 0);
            } while (__builtin_expect(!ok, 0));
#pragma unroll
            for (int s = 0; s < 8; ++s) {
                uint p0 = (uint)(vv[s * 4 + 0] & 0xFFFFu) | (((uint)(vv[s * 4 + 0] >> 32)) << 16);
                uint p1 = (uint)(vv[s * 4 + 1] & 0xFFFFu) | (((uint)(vv[s * 4 + 1] >> 32)) << 16);
                uint p2 = (uint)(vv[s * 4 + 2] & 0xFFFFu) | (((uint)(vv[s * 4 + 2] >> 32)) << 16);
                uint p3 = (uint)(vv[s * 4 + 3] & 0xFFFFu) | (((uint)(vv[s * 4 + 3] >> 32)) << 16);
                uint4 pk = {p0, p1, p2, p3};
                bf16x8 bh = __builtin_bit_cast(bf16x8, pk);
                if (s & 1)
                    acc2 = __builtin_amdgcn_mfma_f32_16x16x32_bf16(af[2 + s], bh, acc2, 0, 0, 0);
                else
                    acc = __builtin_amdgcn_mfma_f32_16x16x32_bf16(af[2 + s], bh, acc, 0, 0, 0);
            }
        }
        float gi = acc[0] + acc2[0] + bi, gf = acc[1] + acc2[1] + bf2;
        float gg = acc[2] + acc2[2] + bg, go = acc[3] + acc2[3] + bo;
        float ii = sigmoidf_(gi), ff = sigmoidf_(gf), g2 = tanhf_(gg), oo = sigmoidf_(go);
        cs = ff * cs + ii * g2;
        float hv = oo * tanhf_(cs);
        if (t == TC_ - 1) {
            hfin[u * 64 + bb] = hv;  // fp32 final h, [u][b]
        } else {
            ushort hb = f2bf(hv);
            int v1 = __shfl((int)hb, l16 + 16);
            int v2 = __shfl((int)hb, l16 + 32);
            int v3 = __shfl((int)hb, l16 + 48);
            if (quad == 0) {
                uint tg2 = ((uint)t) << 16;
                u64 w0 = (u64)(((uint)hb & 0xFFFFu) | tg2) | ((u64)(((uint)v1 & 0xFFFFu) | tg2) << 32);
                u64 w1 = (u64)(((uint)v2 & 0xFFFFu) | tg2) | ((u64)(((uint)v3 & 0xFFFFu) | tg2) << 32);
                u64* dst = hbuf + ((size_t)(t & 1) * 8192) + (bb * 64 + g) * 2;
                __hip_atomic_store(dst, w0, __ATOMIC_RELAXED, __HIP_MEMORY_SCOPE_AGENT);
                __hip_atomic_store(dst + 1, w1, __ATOMIC_RELAXED, __HIP_MEMORY_SCOPE_AGENT);
            }
        }
    }
}

// ---- Kernel 5: out[b][o] = h_final[:,b] . lin_w[o,:] + lin_b[o] ----
__global__ __launch_bounds__(64) void k_fin(const float* __restrict__ hfin, const float* __restrict__ lw,
                                            const float* __restrict__ lb, float* __restrict__ out) {
    int o = blockIdx.x, b = threadIdx.x;
    float acc = lb[o];
    const float* wp = lw + o * 256;
#pragma unroll 4
    for (int u2 = 0; u2 < 256; ++u2) acc += hfin[u2 * 64 + b] * wp[u2];
    out[b * 10 + o] = acc;
}

extern "C" void kernel_launch(void* const* d_in, const int* in_sizes, int n_in,
                              void* d_out, int out_size, void* d_ws, size_t ws_size,
                              hipStream_t stream) {
    const float* in  = (const float*)d_in[0];
    // d_in[1] ("r") unused
    const float* cw  = (const float*)d_in[2];
    const float* cb  = (const float*)d_in[3];
    const float* wih = (const float*)d_in[4];
    const float* whh = (const float*)d_in[5];
    const float* bih = (const float*)d_in[6];
    const float* bhh = (const float*)d_in[7];
    const float* lw  = (const float*)d_in[8];
    const float* lb  = (const float*)d_in[9];
    float* out = (float*)d_out;

    char* ws = (char*)d_ws;
    float*  sq   = (float*)(ws + 0);          // 32768 B
    u64*    hbuf = (u64*)(ws + 32768);        // 131072 B: 2 parity bufs x 4096 cells x 16B
    float*  bias = (float*)(ws + 163840);     // 4096 B
    float*  hfin = (float*)(ws + 167936);     // 65536 B  [u][b] fp32
    ushort* wbf  = (ushort*)(ws + 233472);    // 655360 B [g][16][320] bf16
    ushort* li   = (ushort*)(ws + 888832);    // 9418752 B [tc][b][72] bf16

    hipMemsetAsync(sq, 0, 32768, stream);
    hipMemsetAsync(hbuf, 0xFF, 131072, stream);  // tag field -> 0xFFFF, never a valid step

    k_sqsum<<<1024, 128, 0, stream>>>(in, sq);
    k_prep<<<1280, 256, 0, stream>>>(wih, whh, bih, bhh, wbf, bias);
    k_conv<<<2048, 256, 0, stream>>>(in, cw, cb, sq, li);
    k_scan<<<64, 256, 0, stream>>>(li, wbf, bias, hbuf, hfin);
    k_fin<<<10, 64, 0, stream>>>(hfin, lw, lb, out);
}

// Round 3
// 5969.046 us; speedup vs baseline: 1.3392x; 1.2476x over previous
//
#include <hip/hip_runtime.h>
#include <stdint.h>

#define B_ 64
#define T_ 2048
#define F_ 128
#define H_ 256
#define TC_ 1022

typedef __bf16 bf16x8 __attribute__((ext_vector_type(8)));
typedef float f32x4 __attribute__((ext_vector_type(4)));
typedef unsigned long long u64;

__device__ __forceinline__ ushort f2bf(float f) {
    uint32_t u = __builtin_bit_cast(uint32_t, f);
    u += 0x7FFFu + ((u >> 16) & 1u);
    return (ushort)(u >> 16);
}
__device__ __forceinline__ float sigmoidf_(float x) { return 1.f / (1.f + __expf(-x)); }
__device__ __forceinline__ float tanhf_(float x) {
    x = fminf(15.f, fmaxf(-15.f, x));
    float e = __expf(2.f * x);
    return (e - 1.f) / (e + 1.f);
}

// ---- Kernel 1: sum of squares over T for F.normalize(dim=1) ----
__global__ __launch_bounds__(128) void k_sqsum(const float* __restrict__ in,
                                               float* __restrict__ sq) {
    int b = blockIdx.x >> 4, tq = blockIdx.x & 15, f = threadIdx.x;
    const float* p = in + ((size_t)b * T_ + (size_t)tq * 128) * F_ + f;
    float acc = 0.f;
#pragma unroll 8
    for (int t = 0; t < 128; ++t) { float v = p[(size_t)t * F_]; acc += v * v; }
    atomicAdd(&sq[b * F_ + f], acc);
}

// ---- Kernel 2: weight repack to bf16 block-row order; bias combine ----
__global__ __launch_bounds__(256) void k_prep(const float* __restrict__ wih, const float* __restrict__ whh,
                                              const float* __restrict__ bih, const float* __restrict__ bhh,
                                              ushort* __restrict__ wbf, float* __restrict__ bias) {
    int e = blockIdx.x * 256 + threadIdx.x;
    if (e < 64 * 16 * 320) {
        int g = e / 5120, m = (e / 320) & 15, k = e % 320;
        int j = (m & 3) * 256 + g * 4 + (m >> 2);  // gate*256 + unit
        float v = (k < 64) ? wih[j * 64 + k] : whh[j * 256 + (k - 64)];
        wbf[e] = f2bf(v);
    }
    if (e < 1024) bias[e] = bih[e] + bhh[e];
}

// ---- Kernel 3: fused normalize + conv1d(K=5,S=2) + bias + relu -> li bf16 [tc][b][72pad] ----
__global__ __launch_bounds__(256) void k_conv(const float* __restrict__ in, const float* __restrict__ cw,
                                              const float* __restrict__ cb, const float* __restrict__ sq,
                                              ushort* __restrict__ li) {
    __shared__ float rn[128];
    __shared__ __align__(16) float xs[67 * 129];
    __shared__ __align__(16) float wl[80 * 68];
    int b = blockIdx.x >> 5, tile = blockIdx.x & 31;
    int tc0 = tile * 32;
    int tid = threadIdx.x;
    if (tid < 128) { float ss = sq[b * 128 + tid]; rn[tid] = 1.f / fmaxf(sqrtf(ss), 1e-12f); }
    __syncthreads();
    const float* ip = in + ((size_t)b * T_ + (size_t)(2 * tc0)) * F_;
    for (int i = tid; i < 67 * 128; i += 256) {
        int r = i >> 7, f = i & 127;
        int t = 2 * tc0 + r;
        xs[r * 129 + f] = (t < T_) ? ip[(size_t)r * F_ + f] * rn[f] : 0.f;
    }
    int cg = tid & 15, tcg = tid >> 4;
    float a00 = 0, a01 = 0, a10 = 0, a11 = 0, a20 = 0, a21 = 0, a30 = 0, a31 = 0;
    for (int fc = 0; fc < 8; ++fc) {
        __syncthreads();
        for (int i = tid; i < 64 * 80; i += 256) {
            int c = i / 80, j = i - c * 80;
            wl[j * 68 + c] = cw[c * 640 + fc * 80 + j];
        }
        __syncthreads();
#pragma unroll
        for (int fi = 0; fi < 16; ++fi) {
#pragma unroll
            for (int k = 0; k < 5; ++k) {
                const float4 w4 = *(const float4*)&wl[(fi * 5 + k) * 68 + cg * 4];
                float x0 = xs[(4 * tcg + k) * 129 + fc * 16 + fi];
                float x1 = xs[(4 * tcg + 2 + k) * 129 + fc * 16 + fi];
                a00 += w4.x * x0; a01 += w4.x * x1;
                a10 += w4.y * x0; a11 += w4.y * x1;
                a20 += w4.z * x0; a21 += w4.z * x1;
                a30 += w4.w * x0; a31 += w4.w * x1;
            }
        }
    }
    float bc0 = cb[cg * 4 + 0], bc1 = cb[cg * 4 + 1], bc2 = cb[cg * 4 + 2], bc3 = cb[cg * 4 + 3];
#pragma unroll
    for (int tt = 0; tt < 2; ++tt) {
        int tc = tc0 + tcg * 2 + tt;
        if (tc < TC_) {
            float v0 = fmaxf((tt ? a01 : a00) + bc0, 0.f);
            float v1 = fmaxf((tt ? a11 : a10) + bc1, 0.f);
            float v2 = fmaxf((tt ? a21 : a20) + bc2, 0.f);
            float v3 = fmaxf((tt ? a31 : a30) + bc3, 0.f);
            uint2 pk;
            pk.x = (uint32_t)f2bf(v0) | ((uint32_t)f2bf(v1) << 16);
            pk.y = (uint32_t)f2bf(v2) | ((uint32_t)f2bf(v3) << 16);
            *reinterpret_cast<uint2*>(&li[((size_t)tc * 64 + b) * 72 + cg * 4]) = pk;
        }
    }
}

// ---- Kernel 4: wave-autonomous LSTM scan. 64 blocks x 256 thr. Block g owns units [4g,4g+4);
// wave w owns batches [16w,16w+16). No LDS/syncthreads/fences. h exchanged through LLC via
// relaxed agent atomics: tagged 8B data cells (bf16 h | step<<16, x2) + a monotone per-producer
// 4B flag. Consumers poll the 64 flags (1 load/lane + ballot, 256B/wave/pass) and only then do
// the single 16KB tagged data pass (tag check catches flag-before-data reordering; retry).
// Monotone flags (value = steps completed) are deadlock-free; parity double-buffering + the
// flag ordering chain enforce WAR safety on data cells.
__global__ __launch_bounds__(256) void k_scan(const ushort* __restrict__ li,
                                              const ushort* __restrict__ wbf,
                                              const float* __restrict__ bias,
                                              u64* __restrict__ hbuf,
                                              uint* __restrict__ flags,
                                              float* __restrict__ hfin) {
    int g = blockIdx.x;
    int tid = threadIdx.x;
    int lane = tid & 63, wave = tid >> 6, l16 = lane & 15, quad = lane >> 4;
    int bb = wave * 16 + l16;
    int u = g * 4 + quad;
    // Stationary A-fragments (weights) for the whole scan.
    bf16x8 af[10];
    const ushort* wp = wbf + ((size_t)g * 16 + l16) * 320 + quad * 8;
#pragma unroll
    for (int s = 0; s < 10; ++s) af[s] = *(const bf16x8*)(wp + s * 32);
    float bi = bias[u], bf2 = bias[256 + u], bg = bias[512 + u], bo = bias[768 + u];
    float cs = 0.f;
    uint* myflag = flags + wave * 64 + g;
    const uint* fl = flags + wave * 64;
#pragma unroll 1
    for (int t = 0; t < TC_; ++t) {
        // xt fragments: plain cached loads, independent of the h exchange -> issue first.
        const ushort* xp = li + ((size_t)t * 64 + bb) * 72 + quad * 8;
        bf16x8 bx0 = *(const bf16x8*)xp;
        bf16x8 bx1 = *(const bf16x8*)(xp + 32);
        f32x4 acc = {0.f, 0.f, 0.f, 0.f};
        f32x4 acc2 = {0.f, 0.f, 0.f, 0.f};
        acc = __builtin_amdgcn_mfma_f32_16x16x32_bf16(af[0], bx0, acc, 0, 0, 0);
        acc2 = __builtin_amdgcn_mfma_f32_16x16x32_bf16(af[1], bx1, acc2, 0, 0, 0);
        if (t > 0) {
            uint tg = (uint)(t - 1);
            // Phase 1: cheap flag poll. flags[w][g'] >= t  <=>  producer g' finished step t-1.
            while (true) {
                uint f = __hip_atomic_load(fl + lane, __ATOMIC_RELAXED, __HIP_MEMORY_SCOPE_AGENT);
                if (__ballot(f >= (uint)t) == ~0ull) break;
            }
            // Phase 2: tagged data pass (normally 1 iteration).
            const u64* base = hbuf + ((size_t)(tg & 1) * 8192) + bb * 128 + quad * 4;
            u64 vv[32];
            bool ok;
            do {
#pragma unroll
                for (int s = 0; s < 8; ++s)
#pragma unroll
                    for (int j = 0; j < 4; ++j)
                        vv[s * 4 + j] = __hip_atomic_load(base + 16 * s + j,
                                                          __ATOMIC_RELAXED, __HIP_MEMORY_SCOPE_AGENT);
                uint m = 0;
#pragma unroll
                for (int i = 0; i < 32; ++i) m |= ((uint)(vv[i] >> 48)) ^ tg;
                ok = (m == 0);
            } while (__builtin_expect(!ok, 0));
#pragma unroll
            for (int s = 0; s < 8; ++s) {
                uint p0 = (uint)(vv[s * 4 + 0] & 0xFFFFu) | (((uint)(vv[s * 4 + 0] >> 32)) << 16);
                uint p1 = (uint)(vv[s * 4 + 1] & 0xFFFFu) | (((uint)(vv[s * 4 + 1] >> 32)) << 16);
                uint p2 = (uint)(vv[s * 4 + 2] & 0xFFFFu) | (((uint)(vv[s * 4 + 2] >> 32)) << 16);
                uint p3 = (uint)(vv[s * 4 + 3] & 0xFFFFu) | (((uint)(vv[s * 4 + 3] >> 32)) << 16);
                uint4 pk = {p0, p1, p2, p3};
                bf16x8 bh = __builtin_bit_cast(bf16x8, pk);
                if (s & 1)
                    acc2 = __builtin_amdgcn_mfma_f32_16x16x32_bf16(af[2 + s], bh, acc2, 0, 0, 0);
                else
                    acc = __builtin_amdgcn_mfma_f32_16x16x32_bf16(af[2 + s], bh, acc, 0, 0, 0);
            }
        }
        float gi = acc[0] + acc2[0] + bi, gf = acc[1] + acc2[1] + bf2;
        float gg = acc[2] + acc2[2] + bg, go = acc[3] + acc2[3] + bo;
        float ii = sigmoidf_(gi), ff = sigmoidf_(gf), g2 = tanhf_(gg), oo = sigmoidf_(go);
        cs = ff * cs + ii * g2;
        float hv = oo * tanhf_(cs);
        if (t == TC_ - 1) {
            hfin[u * 64 + bb] = hv;  // fp32 final h, [u][b]
        } else {
            ushort hb = f2bf(hv);
            int v1 = __shfl((int)hb, l16 + 16);
            int v2 = __shfl((int)hb, l16 + 32);
            int v3 = __shfl((int)hb, l16 + 48);
            if (quad == 0) {
                uint tg2 = ((uint)t) << 16;
                u64 w0 = (u64)(((uint)hb & 0xFFFFu) | tg2) | ((u64)(((uint)v1 & 0xFFFFu) | tg2) << 32);
                u64 w1 = (u64)(((uint)v2 & 0xFFFFu) | tg2) | ((u64)(((uint)v3 & 0xFFFFu) | tg2) << 32);
                u64* dst = hbuf + ((size_t)(t & 1) * 8192) + (bb * 64 + g) * 2;
                __hip_atomic_store(dst, w0, __ATOMIC_RELAXED, __HIP_MEMORY_SCOPE_AGENT);
                __hip_atomic_store(dst + 1, w1, __ATOMIC_RELAXED, __HIP_MEMORY_SCOPE_AGENT);
            }
            if (lane == 0)
                __hip_atomic_store(myflag, (uint)(t + 1), __ATOMIC_RELAXED, __HIP_MEMORY_SCOPE_AGENT);
        }
    }
}

// ---- Kernel 5: out[b][o] = h_final[:,b] . lin_w[o,:] + lin_b[o] ----
__global__ __launch_bounds__(64) void k_fin(const float* __restrict__ hfin, const float* __restrict__ lw,
                                            const float* __restrict__ lb, float* __restrict__ out) {
    int o = blockIdx.x, b = threadIdx.x;
    float acc = lb[o];
    const float* wp = lw + o * 256;
#pragma unroll 4
    for (int u2 = 0; u2 < 256; ++u2) acc += hfin[u2 * 64 + b] * wp[u2];
    out[b * 10 + o] = acc;
}

extern "C" void kernel_launch(void* const* d_in, const int* in_sizes, int n_in,
                              void* d_out, int out_size, void* d_ws, size_t ws_size,
                              hipStream_t stream) {
    const float* in  = (const float*)d_in[0];
    // d_in[1] ("r") unused
    const float* cw  = (const float*)d_in[2];
    const float* cb  = (const float*)d_in[3];
    const float* wih = (const float*)d_in[4];
    const float* whh = (const float*)d_in[5];
    const float* bih = (const float*)d_in[6];
    const float* bhh = (const float*)d_in[7];
    const float* lw  = (const float*)d_in[8];
    const float* lb  = (const float*)d_in[9];
    float* out = (float*)d_out;

    char* ws = (char*)d_ws;
    float*  sq    = (float*)(ws + 0);          // 32768 B
    u64*    hbuf  = (u64*)(ws + 32768);        // 131072 B: 2 parity bufs x 8192 cells x 8B
    uint*   flags = (uint*)(ws + 163840);      // 1024 B: [wave][64 producers]
    float*  bias  = (float*)(ws + 165888);     // 4096 B
    float*  hfin  = (float*)(ws + 169984);     // 65536 B  [u][b] fp32
    ushort* wbf   = (ushort*)(ws + 235520);    // 655360 B [g][16][320] bf16
    ushort* li    = (ushort*)(ws + 890880);    // 9418752 B [tc][b][72] bf16

    hipMemsetAsync(sq, 0, 32768, stream);
    hipMemsetAsync(hbuf, 0xFF, 131072, stream);  // tag field -> 0xFFFF, never a valid step
    hipMemsetAsync(flags, 0, 1024, stream);      // 0 steps completed

    k_sqsum<<<1024, 128, 0, stream>>>(in, sq);
    k_prep<<<1280, 256, 0, stream>>>(wih, whh, bih, bhh, wbf, bias);
    k_conv<<<2048, 256, 0, stream>>>(in, cw, cb, sq, li);
    k_scan<<<64, 256, 0, stream>>>(li, wbf, bias, hbuf, flags, hfin);
    k_fin<<<10, 64, 0, stream>>>(hfin, lw, lb, out);
}

// Round 5
// 4249.319 us; speedup vs baseline: 1.8812x; 1.4047x over previous
//
#include <hip/hip_runtime.h>
#include <stdint.h>

#define B_ 64
#define T_ 2048
#define F_ 128
#define H_ 256
#define TC_ 1022

typedef __bf16 bf16x8 __attribute__((ext_vector_type(8)));
typedef float f32x4 __attribute__((ext_vector_type(4)));
typedef unsigned long long u64;

__device__ __forceinline__ ushort f2bf(float f) {
    uint32_t u = __builtin_bit_cast(uint32_t, f);
    u += 0x7FFFu + ((u >> 16) & 1u);
    return (ushort)(u >> 16);
}
__device__ __forceinline__ float sigmoidf_(float x) { return 1.f / (1.f + __expf(-x)); }
__device__ __forceinline__ float tanhf_(float x) {
    x = fminf(15.f, fmaxf(-15.f, x));
    float e = __expf(2.f * x);
    return (e - 1.f) / (e + 1.f);
}

// ---- Kernel 1: sum of squares over T for F.normalize(dim=1) ----
__global__ __launch_bounds__(128) void k_sqsum(const float* __restrict__ in,
                                               float* __restrict__ sq) {
    int b = blockIdx.x >> 4, tq = blockIdx.x & 15, f = threadIdx.x;
    const float* p = in + ((size_t)b * T_ + (size_t)tq * 128) * F_ + f;
    float acc = 0.f;
#pragma unroll 8
    for (int t = 0; t < 128; ++t) { float v = p[(size_t)t * F_]; acc += v * v; }
    atomicAdd(&sq[b * F_ + f], acc);
}

// ---- Kernel 2: weight repack to bf16 block-row order; bias combine ----
// wbf[g2][m][k]: g2 = unit>>2 (0..63), m = uu*4+gate, k: [0,64)=w_ih, [64,320)=w_hh
__global__ __launch_bounds__(256) void k_prep(const float* __restrict__ wih, const float* __restrict__ whh,
                                              const float* __restrict__ bih, const float* __restrict__ bhh,
                                              ushort* __restrict__ wbf, float* __restrict__ bias) {
    int e = blockIdx.x * 256 + threadIdx.x;
    if (e < 64 * 16 * 320) {
        int g = e / 5120, m = (e / 320) & 15, k = e % 320;
        int j = (m & 3) * 256 + g * 4 + (m >> 2);  // gate*256 + unit
        float v = (k < 64) ? wih[j * 64 + k] : whh[j * 256 + (k - 64)];
        wbf[e] = f2bf(v);
    }
    if (e < 1024) bias[e] = bih[e] + bhh[e];
}

// ---- Kernel 3: fused normalize + conv1d(K=5,S=2) + bias + relu -> li bf16 [tc][b][72pad] ----
__global__ __launch_bounds__(256) void k_conv(const float* __restrict__ in, const float* __restrict__ cw,
                                              const float* __restrict__ cb, const float* __restrict__ sq,
                                              ushort* __restrict__ li) {
    __shared__ float rn[128];
    __shared__ __align__(16) float xs[67 * 129];
    __shared__ __align__(16) float wl[80 * 68];
    int b = blockIdx.x >> 5, tile = blockIdx.x & 31;
    int tc0 = tile * 32;
    int tid = threadIdx.x;
    if (tid < 128) { float ss = sq[b * 128 + tid]; rn[tid] = 1.f / fmaxf(sqrtf(ss), 1e-12f); }
    __syncthreads();
    const float* ip = in + ((size_t)b * T_ + (size_t)(2 * tc0)) * F_;
    for (int i = tid; i < 67 * 128; i += 256) {
        int r = i >> 7, f = i & 127;
        int t = 2 * tc0 + r;
        xs[r * 129 + f] = (t < T_) ? ip[(size_t)r * F_ + f] * rn[f] : 0.f;
    }
    int cg = tid & 15, tcg = tid >> 4;
    float a00 = 0, a01 = 0, a10 = 0, a11 = 0, a20 = 0, a21 = 0, a30 = 0, a31 = 0;
    for (int fc = 0; fc < 8; ++fc) {
        __syncthreads();
        for (int i = tid; i < 64 * 80; i += 256) {
            int c = i / 80, j = i - c * 80;
            wl[j * 68 + c] = cw[c * 640 + fc * 80 + j];
        }
        __syncthreads();
#pragma unroll
        for (int fi = 0; fi < 16; ++fi) {
#pragma unroll
            for (int k = 0; k < 5; ++k) {
                const float4 w4 = *(const float4*)&wl[(fi * 5 + k) * 68 + cg * 4];
                float x0 = xs[(4 * tcg + k) * 129 + fc * 16 + fi];
                float x1 = xs[(4 * tcg + 2 + k) * 129 + fc * 16 + fi];
                a00 += w4.x * x0; a01 += w4.x * x1;
                a10 += w4.y * x0; a11 += w4.y * x1;
                a20 += w4.z * x0; a21 += w4.z * x1;
                a30 += w4.w * x0; a31 += w4.w * x1;
            }
        }
    }
    float bc0 = cb[cg * 4 + 0], bc1 = cb[cg * 4 + 1], bc2 = cb[cg * 4 + 2], bc3 = cb[cg * 4 + 3];
#pragma unroll
    for (int tt = 0; tt < 2; ++tt) {
        int tc = tc0 + tcg * 2 + tt;
        if (tc < TC_) {
            float v0 = fmaxf((tt ? a01 : a00) + bc0, 0.f);
            float v1 = fmaxf((tt ? a11 : a10) + bc1, 0.f);
            float v2 = fmaxf((tt ? a21 : a20) + bc2, 0.f);
            float v3 = fmaxf((tt ? a31 : a30) + bc3, 0.f);
            uint2 pk;
            pk.x = (uint32_t)f2bf(v0) | ((uint32_t)f2bf(v1) << 16);
            pk.y = (uint32_t)f2bf(v2) | ((uint32_t)f2bf(v3) << 16);
            *reinterpret_cast<uint2*>(&li[((size_t)tc * 64 + b) * 72 + cg * 4]) = pk;
        }
    }
}

// ---- Kernel 4: LSTM scan, 16 blocks x 512 threads (8 waves). Block g owns units
// [16g,16g+16), all 64 batches. Wave w: mi=w&3 (unit quad-group), a=w>>2; wave computes
// TWO 16x16 tiles: batch groups ni=a and ni=a+2 (bb and bb+32), reusing its A-fragments.
// h exchange via MALL: tagged u64 cells [b][u/2] = (h_even|t<<16)|((h_odd|t<<16)<<32),
// relaxed agent atomics, fire-and-forget. Fused detect+read: each thread bulk-loads 16
// coalesced cells, retries until all tags==t-1 (bounded guard -> garbage not hang), then
// stages to LDS; fragments via ds_read_b128. WAR safety: producer writes t+1 into buffer A
// only after observing ALL step-t tags, which requires every wave to have completed its
// poll of buffer A (data already in registers). Parity double-buffer, no ABA (t-3/t-1/t+1).
__global__ __launch_bounds__(512) void k_scan(const ushort* __restrict__ li,
                                              const ushort* __restrict__ wbf,
                                              const float* __restrict__ bias,
                                              u64* __restrict__ hbuf,
                                              float* __restrict__ hfin) {
    __shared__ __align__(16) ushort Hs[64 * 264];  // h [b][256+8 pad] bf16, rows 528B
    int g = blockIdx.x;
    int tid = threadIdx.x;
    int lane = tid & 63, wave = tid >> 6, l16 = lane & 15, quad = lane >> 4;
    int mi = wave & 3, a = wave >> 2;  // a in {0,1}
    int bb = a * 16 + l16;             // tile0 batch; tile1 batch = bb+32
    int u = g * 16 + mi * 4 + quad;
    // Stationary A-fragments: the wave's 16 gate-rows (g2 = 4g+mi), k-slice quad*8.
    bf16x8 af[10];
    const ushort* wp = wbf + ((size_t)((g * 4 + mi) * 16 + l16)) * 320 + quad * 8;
#pragma unroll
    for (int s = 0; s < 10; ++s) af[s] = *(const bf16x8*)(wp + s * 32);
    float bi = bias[u], bf2 = bias[256 + u], bg = bias[512 + u], bo = bias[768 + u];
    float cs0 = 0.f, cs1 = 0.f;
#pragma unroll 1
    for (int t = 0; t < TC_; ++t) {
        // xt fragments for both tiles: plain cached loads, independent of h exchange.
        const ushort* xp0 = li + ((size_t)t * 64 + bb) * 72 + quad * 8;
        const ushort* xp1 = xp0 + 32 * 72;
        bf16x8 x00 = *(const bf16x8*)xp0;
        bf16x8 x01 = *(const bf16x8*)(xp0 + 32);
        bf16x8 x10 = *(const bf16x8*)xp1;
        bf16x8 x11 = *(const bf16x8*)(xp1 + 32);
        f32x4 a00 = {0.f, 0.f, 0.f, 0.f}, a01 = {0.f, 0.f, 0.f, 0.f};
        f32x4 a10 = {0.f, 0.f, 0.f, 0.f}, a11 = {0.f, 0.f, 0.f, 0.f};
        a00 = __builtin_amdgcn_mfma_f32_16x16x32_bf16(af[0], x00, a00, 0, 0, 0);
        a10 = __builtin_amdgcn_mfma_f32_16x16x32_bf16(af[0], x10, a10, 0, 0, 0);
        a01 = __builtin_amdgcn_mfma_f32_16x16x32_bf16(af[1], x01, a01, 0, 0, 0);
        a11 = __builtin_amdgcn_mfma_f32_16x16x32_bf16(af[1], x11, a11, 0, 0, 0);
        if (t > 0) {
            uint tg = (uint)(t - 1);
            const u64* src = hbuf + ((size_t)(tg & 1) << 13);
            u64 vv[16];
            bool ok;
            int guard = 0;
            do {
#pragma unroll
                for (int k = 0; k < 16; ++k) {
                    int idx = (((k + g) & 15) << 9) + tid;  // block-staggered, lane-coalesced
                    vv[k] = __hip_atomic_load(src + idx, __ATOMIC_RELAXED, __HIP_MEMORY_SCOPE_AGENT);
                }
                ok = true;
#pragma unroll
                for (int k = 0; k < 16; ++k)
                    ok = ok && ((((uint)(vv[k] >> 16) & 0xFFFFu) == tg) &
                                ((uint)(vv[k] >> 48) == tg));
            } while (!__all(ok) && ++guard < (1 << 14));
            __syncthreads();  // B1: prior step's frag ds_reads done before overwrite
#pragma unroll
            for (int k = 0; k < 16; ++k) {
                int idx = (((k + g) & 15) << 9) + tid;
                int b = idx >> 7, c = idx & 127;  // cell -> batch b, unit pair 2c,2c+1
                uint pk = ((uint)vv[k] & 0xFFFFu) | (((uint)(vv[k] >> 32) & 0xFFFFu) << 16);
                *(uint*)&Hs[b * 264 + c * 2] = pk;
            }
            __syncthreads();  // B2: LDS h tile ready
            const ushort* h0 = &Hs[bb * 264 + quad * 8];
            const ushort* h1 = h0 + 32 * 264;
#pragma unroll
            for (int s = 0; s < 8; ++s) {
                bf16x8 bh0 = *(const bf16x8*)(h0 + s * 32);
                bf16x8 bh1 = *(const bf16x8*)(h1 + s * 32);
                if (s & 1) {
                    a01 = __builtin_amdgcn_mfma_f32_16x16x32_bf16(af[2 + s], bh0, a01, 0, 0, 0);
                    a11 = __builtin_amdgcn_mfma_f32_16x16x32_bf16(af[2 + s], bh1, a11, 0, 0, 0);
                } else {
                    a00 = __builtin_amdgcn_mfma_f32_16x16x32_bf16(af[2 + s], bh0, a00, 0, 0, 0);
                    a10 = __builtin_amdgcn_mfma_f32_16x16x32_bf16(af[2 + s], bh1, a10, 0, 0, 0);
                }
            }
        }
#pragma unroll
        for (int j = 0; j < 2; ++j) {
            f32x4& p = j ? a10 : a00;
            f32x4& q = j ? a11 : a01;
            float& cs = j ? cs1 : cs0;
            int bbj = bb + 32 * j;
            float gi = p[0] + q[0] + bi, gf = p[1] + q[1] + bf2;
            float gg = p[2] + q[2] + bg, go = p[3] + q[3] + bo;
            float ii = sigmoidf_(gi), ff = sigmoidf_(gf), g2 = tanhf_(gg), oo = sigmoidf_(go);
            cs = ff * cs + ii * g2;
            float hv = oo * tanhf_(cs);
            if (t == TC_ - 1) {
                hfin[u * 64 + bbj] = hv;  // fp32 final h, [u][b]
            } else {
                ushort hb = f2bf(hv);
                int vp = __shfl((int)hb, lane + 16);  // even quads grab odd-quad partner
                if ((quad & 1) == 0) {
                    uint tg2 = ((uint)t) << 16;
                    u64 w = (u64)(((uint)hb & 0xFFFFu) | tg2) |
                            ((u64)(((uint)vp & 0xFFFFu) | tg2) << 32);
                    int col = g * 8 + mi * 2 + (quad >> 1);
                    u64* dst = hbuf + ((size_t)(t & 1) << 13) + (size_t)bbj * 128 + col;
                    __hip_atomic_store(dst, w, __ATOMIC_RELAXED, __HIP_MEMORY_SCOPE_AGENT);
                }
            }
        }
    }
}

// ---- Kernel 5: out[b][o] = h_final[:,b] . lin_w[o,:] + lin_b[o] ----
__global__ __launch_bounds__(64) void k_fin(const float* __restrict__ hfin, const float* __restrict__ lw,
                                            const float* __restrict__ lb, float* __restrict__ out) {
    int o = blockIdx.x, b = threadIdx.x;
    float acc = lb[o];
    const float* wp = lw + o * 256;
#pragma unroll 4
    for (int u2 = 0; u2 < 256; ++u2) acc += hfin[u2 * 64 + b] * wp[u2];
    out[b * 10 + o] = acc;
}

extern "C" void kernel_launch(void* const* d_in, const int* in_sizes, int n_in,
                              void* d_out, int out_size, void* d_ws, size_t ws_size,
                              hipStream_t stream) {
    const float* in  = (const float*)d_in[0];
    // d_in[1] ("r") unused
    const float* cw  = (const float*)d_in[2];
    const float* cb  = (const float*)d_in[3];
    const float* wih = (const float*)d_in[4];
    const float* whh = (const float*)d_in[5];
    const float* bih = (const float*)d_in[6];
    const float* bhh = (const float*)d_in[7];
    const float* lw  = (const float*)d_in[8];
    const float* lb  = (const float*)d_in[9];
    float* out = (float*)d_out;

    char* ws = (char*)d_ws;
    float*  sq   = (float*)(ws + 0);          // 32768 B
    u64*    hbuf = (u64*)(ws + 32768);        // 131072 B: 2 parity x 8192 cells x 8B
    float*  bias = (float*)(ws + 163840);     // 4096 B
    float*  hfin = (float*)(ws + 167936);     // 65536 B  [u][b] fp32
    ushort* wbf  = (ushort*)(ws + 233472);    // 655360 B [g2][16][320] bf16
    ushort* li   = (ushort*)(ws + 888832);    // 9418752 B [tc][b][72] bf16

    hipMemsetAsync(sq, 0, 32768, stream);
    hipMemsetAsync(hbuf, 0xFF, 131072, stream);  // tag fields -> 0xFFFF, never a valid step

    k_sqsum<<<1024, 128, 0, stream>>>(in, sq);
    k_prep<<<1280, 256, 0, stream>>>(wih, whh, bih, bhh, wbf, bias);
    k_conv<<<2048, 256, 0, stream>>>(in, cw, cb, sq, li);
    k_scan<<<16, 512, 0, stream>>>(li, wbf, bias, hbuf, hfin);
    k_fin<<<10, 64, 0, stream>>>(hfin, lw, lb, out);
}

// Round 6
// 3663.610 us; speedup vs baseline: 2.1820x; 1.1599x over previous
//
#include <hip/hip_runtime.h>
#include <stdint.h>

#define B_ 64
#define T_ 2048
#define F_ 128
#define H_ 256
#define TC_ 1022

typedef __bf16 bf16x8 __attribute__((ext_vector_type(8)));
typedef float f32x4 __attribute__((ext_vector_type(4)));
typedef unsigned long long u64;

__device__ __forceinline__ ushort f2bf(float f) {
    uint32_t u = __builtin_bit_cast(uint32_t, f);
    u += 0x7FFFu + ((u >> 16) & 1u);
    return (ushort)(u >> 16);
}
__device__ __forceinline__ float sigmoidf_(float x) { return 1.f / (1.f + __expf(-x)); }
__device__ __forceinline__ float tanhf_(float x) {
    x = fminf(15.f, fmaxf(-15.f, x));
    float e = __expf(2.f * x);
    return (e - 1.f) / (e + 1.f);
}

// ---- Kernel 1: sum of squares over T for F.normalize(dim=1) ----
__global__ __launch_bounds__(128) void k_sqsum(const float* __restrict__ in,
                                               float* __restrict__ sq) {
    int b = blockIdx.x >> 4, tq = blockIdx.x & 15, f = threadIdx.x;
    const float* p = in + ((size_t)b * T_ + (size_t)tq * 128) * F_ + f;
    float acc = 0.f;
#pragma unroll 8
    for (int t = 0; t < 128; ++t) { float v = p[(size_t)t * F_]; acc += v * v; }
    atomicAdd(&sq[b * F_ + f], acc);
}

// ---- Kernel 2: weight repack to bf16 block-row order; bias combine ----
// wbf[g2][m][k]: g2 = unit>>2 (0..63), m = uu*4+gate, k: [0,64)=w_ih, [64,320)=w_hh
__global__ __launch_bounds__(256) void k_prep(const float* __restrict__ wih, const float* __restrict__ whh,
                                              const float* __restrict__ bih, const float* __restrict__ bhh,
                                              ushort* __restrict__ wbf, float* __restrict__ bias) {
    int e = blockIdx.x * 256 + threadIdx.x;
    if (e < 64 * 16 * 320) {
        int g = e / 5120, m = (e / 320) & 15, k = e % 320;
        int j = (m & 3) * 256 + g * 4 + (m >> 2);  // gate*256 + unit
        float v = (k < 64) ? wih[j * 64 + k] : whh[j * 256 + (k - 64)];
        wbf[e] = f2bf(v);
    }
    if (e < 1024) bias[e] = bih[e] + bhh[e];
}

// ---- Kernel 3: fused normalize + conv1d(K=5,S=2) + bias + relu -> li bf16 [tc][b][72pad] ----
__global__ __launch_bounds__(256) void k_conv(const float* __restrict__ in, const float* __restrict__ cw,
                                              const float* __restrict__ cb, const float* __restrict__ sq,
                                              ushort* __restrict__ li) {
    __shared__ float rn[128];
    __shared__ __align__(16) float xs[67 * 129];
    __shared__ __align__(16) float wl[80 * 68];
    int b = blockIdx.x >> 5, tile = blockIdx.x & 31;
    int tc0 = tile * 32;
    int tid = threadIdx.x;
    if (tid < 128) { float ss = sq[b * 128 + tid]; rn[tid] = 1.f / fmaxf(sqrtf(ss), 1e-12f); }
    __syncthreads();
    const float* ip = in + ((size_t)b * T_ + (size_t)(2 * tc0)) * F_;
    for (int i = tid; i < 67 * 128; i += 256) {
        int r = i >> 7, f = i & 127;
        int t = 2 * tc0 + r;
        xs[r * 129 + f] = (t < T_) ? ip[(size_t)r * F_ + f] * rn[f] : 0.f;
    }
    int cg = tid & 15, tcg = tid >> 4;
    float a00 = 0, a01 = 0, a10 = 0, a11 = 0, a20 = 0, a21 = 0, a30 = 0, a31 = 0;
    for (int fc = 0; fc < 8; ++fc) {
        __syncthreads();
        for (int i = tid; i < 64 * 80; i += 256) {
            int c = i / 80, j = i - c * 80;
            wl[j * 68 + c] = cw[c * 640 + fc * 80 + j];
        }
        __syncthreads();
#pragma unroll
        for (int fi = 0; fi < 16; ++fi) {
#pragma unroll
            for (int k = 0; k < 5; ++k) {
                const float4 w4 = *(const float4*)&wl[(fi * 5 + k) * 68 + cg * 4];
                float x0 = xs[(4 * tcg + k) * 129 + fc * 16 + fi];
                float x1 = xs[(4 * tcg + 2 + k) * 129 + fc * 16 + fi];
                a00 += w4.x * x0; a01 += w4.x * x1;
                a10 += w4.y * x0; a11 += w4.y * x1;
                a20 += w4.z * x0; a21 += w4.z * x1;
                a30 += w4.w * x0; a31 += w4.w * x1;
            }
        }
    }
    float bc0 = cb[cg * 4 + 0], bc1 = cb[cg * 4 + 1], bc2 = cb[cg * 4 + 2], bc3 = cb[cg * 4 + 3];
#pragma unroll
    for (int tt = 0; tt < 2; ++tt) {
        int tc = tc0 + tcg * 2 + tt;
        if (tc < TC_) {
            float v0 = fmaxf((tt ? a01 : a00) + bc0, 0.f);
            float v1 = fmaxf((tt ? a11 : a10) + bc1, 0.f);
            float v2 = fmaxf((tt ? a21 : a20) + bc2, 0.f);
            float v3 = fmaxf((tt ? a31 : a30) + bc3, 0.f);
            uint2 pk;
            pk.x = (uint32_t)f2bf(v0) | ((uint32_t)f2bf(v1) << 16);
            pk.y = (uint32_t)f2bf(v2) | ((uint32_t)f2bf(v3) << 16);
            *reinterpret_cast<uint2*>(&li[((size_t)tc * 64 + b) * 72 + cg * 4]) = pk;
        }
    }
}

// ---- Kernel 4: LSTM scan, 16 blocks x 512 threads (8 waves). Block g owns units
// [16g,16g+16), all 64 batches. Wave w: mi=w&3, a=w>>2; computes TWO 16x16 tiles
// (batches bb and bb+32). Exchange protocol (no tags, flag-gated):
//   producer: issue h stores (parity t&1) -> s_waitcnt vmcnt(0) (acked at MALL)
//             -> per-WAVE flag := t+1 (relaxed agent atomic).
//   consumer: poll all 128 wave-flags >= t (2 atomic loads/lane + ballot, ~8 lines)
//             -> ONE coalesced bulk read of 4096 u64 cells (guaranteed visible: data
//             acked before flag issued; bulk issues control-dependent on flag)
//             -> stage raw cells to LDS -> ds_read_b128 fragments.
// WAR: parity double buffer; flags>=t proves every wave finished step t-2 memory ops
// (drain covers them), so overwriting parity t&1 and the LDS tile is safe. One
// __syncthreads per step (stage-write -> frag-read). Poll guarded: fails absmax, not hangs.
__global__ __launch_bounds__(512) void k_scan(const ushort* __restrict__ li,
                                              const ushort* __restrict__ wbf,
                                              const float* __restrict__ bias,
                                              u64* __restrict__ hbuf,
                                              uint* __restrict__ flags,
                                              float* __restrict__ hfin) {
    __shared__ __align__(16) ushort Hs[64 * 264];  // h [b][256+8 pad] bf16, rows 528B
    int g = blockIdx.x;
    int tid = threadIdx.x;
    int lane = tid & 63, wave = tid >> 6, l16 = lane & 15, quad = lane >> 4;
    int mi = wave & 3, a = wave >> 2;  // a in {0,1}
    int bb = a * 16 + l16;             // tile0 batch; tile1 batch = bb+32
    int u = g * 16 + mi * 4 + quad;
    // Stationary A-fragments: the wave's 16 gate-rows (g2 = 4g+mi), k-slice quad*8.
    bf16x8 af[10];
    const ushort* wp = wbf + ((size_t)((g * 4 + mi) * 16 + l16)) * 320 + quad * 8;
#pragma unroll
    for (int s = 0; s < 10; ++s) af[s] = *(const bf16x8*)(wp + s * 32);
    float bi = bias[u], bf2 = bias[256 + u], bg = bias[512 + u], bo = bias[768 + u];
    float cs0 = 0.f, cs1 = 0.f;
    uint* myflag = flags + g * 8 + wave;
#pragma unroll 1
    for (int t = 0; t < TC_; ++t) {
        // xt fragments for both tiles: plain cached loads, overlap the poll.
        const ushort* xp0 = li + ((size_t)t * 64 + bb) * 72 + quad * 8;
        const ushort* xp1 = xp0 + 32 * 72;
        bf16x8 x00 = *(const bf16x8*)xp0;
        bf16x8 x01 = *(const bf16x8*)(xp0 + 32);
        bf16x8 x10 = *(const bf16x8*)xp1;
        bf16x8 x11 = *(const bf16x8*)(xp1 + 32);
        f32x4 a00 = {0.f, 0.f, 0.f, 0.f}, a01 = {0.f, 0.f, 0.f, 0.f};
        f32x4 a10 = {0.f, 0.f, 0.f, 0.f}, a11 = {0.f, 0.f, 0.f, 0.f};
        a00 = __builtin_amdgcn_mfma_f32_16x16x32_bf16(af[0], x00, a00, 0, 0, 0);
        a10 = __builtin_amdgcn_mfma_f32_16x16x32_bf16(af[0], x10, a10, 0, 0, 0);
        a01 = __builtin_amdgcn_mfma_f32_16x16x32_bf16(af[1], x01, a01, 0, 0, 0);
        a11 = __builtin_amdgcn_mfma_f32_16x16x32_bf16(af[1], x11, a11, 0, 0, 0);
        if (t > 0) {
            // Phase 1: flag poll — all 128 wave-flags must reach t.
            int guard = 0;
            while (true) {
                uint f0 = __hip_atomic_load(flags + lane, __ATOMIC_RELAXED, __HIP_MEMORY_SCOPE_AGENT);
                uint f1 = __hip_atomic_load(flags + 64 + lane, __ATOMIC_RELAXED, __HIP_MEMORY_SCOPE_AGENT);
                bool ok = (f0 >= (uint)t) && (f1 >= (uint)t);
                if (__ballot(ok) == ~0ull || ++guard >= (1 << 15)) break;
            }
            // Phase 2: single coalesced bulk read of the whole h image (4096 cells).
            const u64* src = hbuf + ((size_t)((t - 1) & 1) << 12);
            u64 vv[8];
#pragma unroll
            for (int k = 0; k < 8; ++k) {
                int idx = (((k + g) & 7) << 9) + tid;  // block-staggered, lane-coalesced
                vv[k] = __hip_atomic_load(src + idx, __ATOMIC_RELAXED, __HIP_MEMORY_SCOPE_AGENT);
            }
            // Stage raw cells into LDS: cell = 4 packed bf16 of [b][4u-group].
#pragma unroll
            for (int k = 0; k < 8; ++k) {
                int idx = (((k + g) & 7) << 9) + tid;
                int b = idx >> 6, c = idx & 63;
                *(uint2*)&Hs[b * 264 + c * 4] = __builtin_bit_cast(uint2, vv[k]);
            }
            __syncthreads();  // LDS h tile ready
            const ushort* h0 = &Hs[bb * 264 + quad * 8];
            const ushort* h1 = h0 + 32 * 264;
#pragma unroll
            for (int s = 0; s < 8; ++s) {
                bf16x8 bh0 = *(const bf16x8*)(h0 + s * 32);
                bf16x8 bh1 = *(const bf16x8*)(h1 + s * 32);
                if (s & 1) {
                    a01 = __builtin_amdgcn_mfma_f32_16x16x32_bf16(af[2 + s], bh0, a01, 0, 0, 0);
                    a11 = __builtin_amdgcn_mfma_f32_16x16x32_bf16(af[2 + s], bh1, a11, 0, 0, 0);
                } else {
                    a00 = __builtin_amdgcn_mfma_f32_16x16x32_bf16(af[2 + s], bh0, a00, 0, 0, 0);
                    a10 = __builtin_amdgcn_mfma_f32_16x16x32_bf16(af[2 + s], bh1, a10, 0, 0, 0);
                }
            }
        }
        uint pk01 = 0, pk23 = 0;  // packed h pairs (valid on quads 0 and 2)
        float hv0 = 0.f, hv1 = 0.f;
#pragma unroll
        for (int j = 0; j < 2; ++j) {
            f32x4& p = j ? a10 : a00;
            f32x4& q = j ? a11 : a01;
            float& cs = j ? cs1 : cs0;
            float gi = p[0] + q[0] + bi, gf = p[1] + q[1] + bf2;
            float gg = p[2] + q[2] + bg, go = p[3] + q[3] + bo;
            float ii = sigmoidf_(gi), ff = sigmoidf_(gf), g2 = tanhf_(gg), oo = sigmoidf_(go);
            cs = ff * cs + ii * g2;
            float hv = oo * tanhf_(cs);
            if (j) hv1 = hv; else hv0 = hv;
        }
        if (t == TC_ - 1) {
            hfin[u * 64 + bb] = hv0;
            hfin[u * 64 + bb + 32] = hv1;
        } else {
            u64* dstbase = hbuf + ((size_t)(t & 1) << 12);
#pragma unroll
            for (int j = 0; j < 2; ++j) {
                ushort hb = f2bf(j ? hv1 : hv0);
                // gather quads 0..3 for same (l16): two shfl rounds
                uint v1 = (uint)__shfl((int)hb, lane + 16);             // quad q gets q+1
                uint pk = ((uint)hb & 0xFFFFu) | (v1 << 16);            // valid on quads 0,2
                uint v2 = (uint)__shfl((int)pk, lane + 32);             // quad 0 gets quad 2's pair
                if (quad == 0) {
                    u64 w = (u64)pk | ((u64)v2 << 32);                  // units 4G..4G+3 packed
                    int bbj = bb + 32 * j;
                    __hip_atomic_store(dstbase + bbj * 64 + (g * 4 + mi), w,
                                       __ATOMIC_RELAXED, __HIP_MEMORY_SCOPE_AGENT);
                }
            }
            __builtin_amdgcn_s_waitcnt(0x0F70);  // vmcnt(0): h stores acked at coherent point
            if (lane == 0)
                __hip_atomic_store(myflag, (uint)(t + 1), __ATOMIC_RELAXED, __HIP_MEMORY_SCOPE_AGENT);
        }
    }
}

// ---- Kernel 5: out[b][o] = h_final[:,b] . lin_w[o,:] + lin_b[o] ----
__global__ __launch_bounds__(64) void k_fin(const float* __restrict__ hfin, const float* __restrict__ lw,
                                            const float* __restrict__ lb, float* __restrict__ out) {
    int o = blockIdx.x, b = threadIdx.x;
    float acc = lb[o];
    const float* wp = lw + o * 256;
#pragma unroll 4
    for (int u2 = 0; u2 < 256; ++u2) acc += hfin[u2 * 64 + b] * wp[u2];
    out[b * 10 + o] = acc;
}

extern "C" void kernel_launch(void* const* d_in, const int* in_sizes, int n_in,
                              void* d_out, int out_size, void* d_ws, size_t ws_size,
                              hipStream_t stream) {
    const float* in  = (const float*)d_in[0];
    // d_in[1] ("r") unused
    const float* cw  = (const float*)d_in[2];
    const float* cb  = (const float*)d_in[3];
    const float* wih = (const float*)d_in[4];
    const float* whh = (const float*)d_in[5];
    const float* bih = (const float*)d_in[6];
    const float* bhh = (const float*)d_in[7];
    const float* lw  = (const float*)d_in[8];
    const float* lb  = (const float*)d_in[9];
    float* out = (float*)d_out;

    char* ws = (char*)d_ws;
    float*  sq    = (float*)(ws + 0);          // 32768 B
    u64*    hbuf  = (u64*)(ws + 32768);        // 65536 B: 2 parity x 4096 cells x 8B
    uint*   flags = (uint*)(ws + 98304);       // 512 B: 128 per-wave flags
    float*  bias  = (float*)(ws + 102400);     // 4096 B
    float*  hfin  = (float*)(ws + 106496);     // 65536 B  [u][b] fp32
    ushort* wbf   = (ushort*)(ws + 172032);    // 655360 B [g2][16][320] bf16
    ushort* li    = (ushort*)(ws + 827392);    // 9418752 B [tc][b][72] bf16

    hipMemsetAsync(sq, 0, 32768, stream);
    hipMemsetAsync(flags, 0, 512, stream);  // 0 steps completed; hbuf needs no init (flag-gated)

    k_sqsum<<<1024, 128, 0, stream>>>(in, sq);
    k_prep<<<1280, 256, 0, stream>>>(wih, whh, bih, bhh, wbf, bias);
    k_conv<<<2048, 256, 0, stream>>>(in, cw, cb, sq, li);
    k_scan<<<16, 512, 0, stream>>>(li, wbf, bias, hbuf, flags, hfin);
    k_fin<<<10, 64, 0, stream>>>(hfin, lw, lb, out);
}